// Round 6
// baseline (137.899 us; speedup 1.0000x reference)
//
#include <hip/hip_runtime.h>
#include <math.h>

#define N_NODES 2000
#define E_DIM   128
#define QKV_W   384
#define LDA     36   // A-tile leading dim pad

// ---------------------------------------------------------------------------
// Kernel 1: fused prep + qkv. (unchanged — not the bottleneck)
// ---------------------------------------------------------------------------
__global__ __launch_bounds__(256) void prep_qkv_kernel(
    const float* __restrict__ x, const float* __restrict__ coords9,
    const float* __restrict__ ps, const float* __restrict__ pe_w,
    const float* __restrict__ pe_b, const float* __restrict__ pe_g,
    const float* __restrict__ pe_bt, const float* __restrict__ in_w,
    const float* __restrict__ in_b,
    float* __restrict__ cx_, float* __restrict__ cy_, float* __restrict__ cz_,
    float* __restrict__ qkv)
{
    __shared__ __align__(16) float As[E_DIM * LDA]; // As[c][r]
    int tid = threadIdx.x;
    int rt = blockIdx.x / 3, ct = blockIdx.x % 3;
    int rbase = rt * 32, cbase = ct * 128;
    int g = tid >> 5, lane = tid & 31;

    #pragma unroll
    for (int rr = 0; rr < 4; ++rr) {
        int rl = rr * 8 + g;
        int row = rbase + rl;
        bool vr = (row < N_NODES);
        float cx = 0.f, cy = 0.f, cz = 0.f;
        if (vr) {
            const float* c9 = coords9 + row * 9;
            cx = (c9[0] + c9[3] + c9[6]) * (1.0f / 3.0f);
            cy = (c9[1] + c9[4] + c9[7]) * (1.0f / 3.0f);
            cz = (c9[2] + c9[5] + c9[8]) * (1.0f / 3.0f);
        }
        if (ct == 0 && vr && lane == 0) { cx_[row] = cx; cy_[row] = cy; cz_[row] = cz; }

        #pragma unroll
        for (int k = 0; k < 3; ++k) {
            int c = lane + 32 * k;
            float v = vr ? (x[row * E_DIM + c] + ps[c]) : 0.f;
            As[c * LDA + rl] = v;
        }

        int j = lane;
        float h = cx * pe_w[j] + cy * pe_w[32 + j] + cz * pe_w[64 + j] + pe_b[j];
        float ge = 0.5f * h * (1.0f + erff(h * 0.7071067811865476f)); // exact GELU
        float s = ge;
        #pragma unroll
        for (int m = 16; m >= 1; m >>= 1) s += __shfl_xor(s, m);
        float mu = s * (1.0f / 32.0f);
        float d = ge - mu;
        float v2 = d * d;
        #pragma unroll
        for (int m = 16; m >= 1; m >>= 1) v2 += __shfl_xor(v2, m);
        float var = v2 * (1.0f / 32.0f);
        float y = d * (1.0f / sqrtf(var + 1e-5f)) * pe_g[j] + pe_bt[j];
        As[(96 + j) * LDA + rl] = vr ? y : 0.f;
    }
    __syncthreads();

    int cg = tid & 31, rg = tid >> 5;
    int c0 = cbase + cg * 4, r0 = rg * 4;
    float acc[4][4];
    #pragma unroll
    for (int i = 0; i < 4; ++i)
        #pragma unroll
        for (int jj = 0; jj < 4; ++jj) acc[i][jj] = 0.f;

    for (int k0 = 0; k0 < 128; k0 += 4) {
        float4 a0 = *(const float4*)&As[(k0 + 0) * LDA + r0];
        float4 a1 = *(const float4*)&As[(k0 + 1) * LDA + r0];
        float4 a2 = *(const float4*)&As[(k0 + 2) * LDA + r0];
        float4 a3 = *(const float4*)&As[(k0 + 3) * LDA + r0];
        #pragma unroll
        for (int ci = 0; ci < 4; ++ci) {
            float4 b = *(const float4*)&in_w[(c0 + ci) * E_DIM + k0];
            acc[0][ci] += a0.x * b.x + a1.x * b.y + a2.x * b.z + a3.x * b.w;
            acc[1][ci] += a0.y * b.x + a1.y * b.y + a2.y * b.z + a3.y * b.w;
            acc[2][ci] += a0.z * b.x + a1.z * b.y + a2.z * b.z + a3.z * b.w;
            acc[3][ci] += a0.w * b.x + a1.w * b.y + a2.w * b.z + a3.w * b.w;
        }
    }

    #pragma unroll
    for (int ri = 0; ri < 4; ++ri) {
        int row = rbase + r0 + ri;
        if (row < N_NODES) {
            float4 o4;
            o4.x = acc[ri][0] + in_b[c0 + 0];
            o4.y = acc[ri][1] + in_b[c0 + 1];
            o4.z = acc[ri][2] + in_b[c0 + 2];
            o4.w = acc[ri][3] + in_b[c0 + 3];
            *(float4*)&qkv[row * QKV_W + c0] = o4;
        }
    }
}

// ---------------------------------------------------------------------------
// Kernel 2 (R6): WAVE-SYNCHRONOUS attn + out-proj. One 64-lane wave per row,
// 4 rows per 256-thread block, grid 500. All LDS is per-wave => zero
// __syncthreads(). The DS pipe executes a wave's LDS ops in order, so
// wave-private LDS RAW needs no barrier; wave_barrier() pins compile-time
// ordering (free at runtime). Selection semantics identical to R2-R5
// (linear-value histogram + exact uint32-key/index tie-break == jax top_k;
// exp(-1e9)==0 in f32 => 32-subset softmax == reference).
// ---------------------------------------------------------------------------
__device__ __forceinline__ float sanitize(float v)
{
    v = (v == v) ? v : 0.f;
    return fminf(fmaxf(v, -1e4f), 1e4f);
}

__global__ __launch_bounds__(256) void attn_proj_kernel(
    const float* __restrict__ cx_, const float* __restrict__ cy_,
    const float* __restrict__ cz_, const float* __restrict__ qkv,
    const float* __restrict__ out_w, const float* __restrict__ out_b,
    float* __restrict__ out)
{
    __shared__ __align__(16) unsigned int hist[4][256];
    __shared__ int eqIdx[4][256];
    __shared__ unsigned int eqKey[4][256];
    __shared__ int topk[4][32];
    __shared__ int cnt[4][2];                 // [0]=sel, [1]=eq
    __shared__ __align__(16) float qs[4][128];
    __shared__ __align__(16) float pr[4][256];
    __shared__ __align__(16) float os[4][128];

    int tid = threadIdx.x;
    int lane = tid & 63, w = tid >> 6;
    int row = blockIdx.x * 4 + w;             // 500*4 = 2000 exactly

    float cix = cx_[row], ciy = cy_[row], ciz = cz_[row];

    // ---- phase A: distance keys (32 per lane, cached in VGPRs) + min/max
    unsigned int kb[32];
    float lmin = __int_as_float(0x7f800000);
    float lmax = __int_as_float(0xff800000);
    {
        #pragma clang fp contract(off)  // match reference bit pattern exactly
        #pragma unroll
        for (int it = 0; it < 32; ++it) {
            int j = lane + 64 * it;
            float key = __int_as_float(0x7f800000);
            if (j < N_NODES) {
                float dx = cix - cx_[j];
                float dy = ciy - cy_[j];
                float dz = ciz - cz_[j];
                float a = dx * dx;
                float b2 = dy * dy;
                float c = dz * dz;
                float d2 = ((a + b2) + c) + 1e-20f;
                key = sqrtf(d2);
                lmin = fminf(lmin, key);
                lmax = fmaxf(lmax, key);
            }
            kb[it] = __float_as_uint(key);
        }
    }
    #pragma unroll
    for (int m = 32; m >= 1; m >>= 1) {
        lmin = fminf(lmin, __shfl_xor(lmin, m));
        lmax = fmaxf(lmax, __shfl_xor(lmax, m));
    }
    float lo = lmin;
    float scale = 255.0f / fmaxf(lmax - lmin, 1e-30f);

    // ---- phase B: zero per-wave hist, then linear-value histogram
    *(uint4*)&hist[w][4 * lane] = make_uint4(0u, 0u, 0u, 0u);
    if (lane == 0) { cnt[w][0] = 0; cnt[w][1] = 0; }
    __builtin_amdgcn_wave_barrier();
    #pragma unroll
    for (int it = 0; it < 32; ++it) {
        int j = lane + 64 * it;
        if (j < N_NODES) {
            float key = __uint_as_float(kb[it]);
            int bin = (int)((key - lo) * scale);
            bin = min(max(bin, 0), 255);
            atomicAdd(&hist[w][bin], 1u);
        }
    }
    __builtin_amdgcn_wave_barrier();

    // ---- phase C: in-wave prefix scan of 256 bins (4/lane), boundary bin
    uint4 h4 = *(const uint4*)&hist[w][4 * lane];
    int s0 = (int)h4.x;
    int s1 = s0 + (int)h4.y;
    int s2 = s1 + (int)h4.z;
    int tot = s2 + (int)h4.w;
    int incl = tot;
    #pragma unroll
    for (int dd = 1; dd < 64; dd <<= 1) {
        int u = __shfl_up(incl, dd);
        if (lane >= dd) incl += u;
    }
    int excl = incl - tot;                    // count in all bins before 4*lane
    int c0 = excl + s0, c1 = excl + s1, c2 = excl + s2, c3 = excl + tot;
    int cand = 256, candN = 0;
    if (excl < 32 && c0 >= 32)      { cand = 4 * lane;     candN = excl; }
    else if (c0 < 32 && c1 >= 32)   { cand = 4 * lane + 1; candN = c0; }
    else if (c1 < 32 && c2 >= 32)   { cand = 4 * lane + 2; candN = c1; }
    else if (c2 < 32 && c3 >= 32)   { cand = 4 * lane + 3; candN = c2; }
    int candV = (cand << 8) | candN;          // candN <= 31 fits in 8 bits
    #pragma unroll
    for (int m = 32; m >= 1; m >>= 1) candV = min(candV, __shfl_xor(candV, m));
    int b = candV >> 8;
    int req = 32 - (candV & 255);             // take req from boundary bin

    // ---- phase D: collect (bins < b in; bin == b to exact resolution); stage q
    #pragma unroll
    for (int it = 0; it < 32; ++it) {
        int j = lane + 64 * it;
        if (j < N_NODES) {
            float key = __uint_as_float(kb[it]);
            int bin = (int)((key - lo) * scale);
            bin = min(max(bin, 0), 255);
            if (bin < b) {
                int p = atomicAdd(&cnt[w][0], 1);
                topk[w][p] = j;
            } else if (bin == b) {
                int e = atomicAdd(&cnt[w][1], 1);
                if (e < 256) { eqIdx[w][e] = j; eqKey[w][e] = kb[it]; }
            }
        }
    }
    qs[w][lane]      = qkv[row * QKV_W + lane];
    qs[w][lane + 64] = qkv[row * QKV_W + lane + 64];
    __builtin_amdgcn_wave_barrier();

    // ---- phase E: boundary bin exact rank on (uint32 key, index)
    int eq = min(cnt[w][1], 256);
    for (int e = lane; e < eq; e += 64) {
        int myIdx = eqIdx[w][e];
        unsigned int myKey = eqKey[w][e];
        int rank = 0;
        for (int u = 0; u < eq; ++u) {
            unsigned int ku = eqKey[w][u];
            rank += (ku < myKey || (ku == myKey && eqIdx[w][u] < myIdx)) ? 1 : 0;
        }
        if (rank < req) {
            int p = atomicAdd(&cnt[w][0], 1);
            topk[w][p] = myIdx;
        }
    }
    __builtin_amdgcn_wave_barrier();

    // ---- load topk once (LDS broadcast reads -> registers)
    int tk[32];
    #pragma unroll
    for (int sl = 0; sl < 32; ++sl) tk[sl] = topk[w][sl];

    // ---- phase F: scores + softmax. 4 (head,slot) pairs per lane.
    // pp-th pair p = lane + 64*pp: lanes 0-31 hold head 2pp, 32-63 head 2pp+1;
    // half-wave xor shuffles reduce within a head.
    #pragma unroll
    for (int pp = 0; pp < 4; ++pp) {
        int p = lane + 64 * pp;
        int hh = p >> 5, sl = p & 31;
        int jj = tk[sl];
        const float4* kp = (const float4*)&qkv[jj * QKV_W + 128 + hh * 16];
        const float4* qp = (const float4*)&qs[w][hh * 16];
        float s = 0.f;
        #pragma unroll
        for (int i = 0; i < 4; ++i) {
            float4 kv = kp[i], qv = qp[i];
            s += qv.x * kv.x + qv.y * kv.y + qv.z * kv.z + qv.w * kv.w;
        }
        s *= 0.25f;                            // 1/sqrt(16)
        float m = s;
        #pragma unroll
        for (int msk = 16; msk >= 1; msk >>= 1) m = fmaxf(m, __shfl_xor(m, msk));
        float pe = expf(s - m);
        float su = pe;
        #pragma unroll
        for (int msk = 16; msk >= 1; msk >>= 1) su += __shfl_xor(su, msk);
        pr[w][p] = pe / su;                    // p == hh*32 + sl
    }
    __builtin_amdgcn_wave_barrier();

    // ---- phase G: o = probs @ v (2 output elements per lane)
    #pragma unroll
    for (int cc = 0; cc < 2; ++cc) {
        int c = lane + 64 * cc;
        int hh = c >> 4;
        float acc = 0.f;
        #pragma unroll
        for (int sl = 0; sl < 32; ++sl) {
            acc += pr[w][hh * 32 + sl] * qkv[tk[sl] * QKV_W + 256 + c];
        }
        os[w][c] = acc;
    }
    __builtin_amdgcn_wave_barrier();

    // ---- phase H: out-projection + sanitize (2 output cols per lane)
    #pragma unroll
    for (int cc = 0; cc < 2; ++cc) {
        int c = lane + 64 * cc;
        const float* wr = out_w + c * E_DIM;
        float a = 0.f;
        #pragma unroll
        for (int e = 0; e < 128; e += 4) {
            float4 w4 = *(const float4*)&wr[e];
            float4 o4 = *(const float4*)&os[w][e];
            a += o4.x * w4.x + o4.y * w4.y + o4.z * w4.z + o4.w * w4.w;
        }
        out[row * E_DIM + c] = sanitize(a + out_b[c]);
    }
}

// ---------------------------------------------------------------------------
extern "C" void kernel_launch(void* const* d_in, const int* in_sizes, int n_in,
                              void* d_out, int out_size, void* d_ws, size_t ws_size,
                              hipStream_t stream)
{
    const float* x      = (const float*)d_in[0];
    const float* coords = (const float*)d_in[1];
    const float* ps     = (const float*)d_in[2];
    const float* pe_w   = (const float*)d_in[3];
    const float* pe_b   = (const float*)d_in[4];
    const float* pe_g   = (const float*)d_in[5];
    const float* pe_bt  = (const float*)d_in[6];
    const float* in_w   = (const float*)d_in[7];
    const float* in_b   = (const float*)d_in[8];
    const float* out_w  = (const float*)d_in[9];
    const float* out_b  = (const float*)d_in[10];
    float* out = (float*)d_out;

    float* ws  = (float*)d_ws;
    float* cxp = ws;            // 2048
    float* cyp = ws + 2048;     // 2048
    float* czp = ws + 4096;     // 2048
    float* qkvb = ws + 6144;    // 2000*384

    prep_qkv_kernel<<<189, 256, 0, stream>>>(x, coords, ps, pe_w, pe_b, pe_g, pe_bt,
                                             in_w, in_b, cxp, cyp, czp, qkvb);
    attn_proj_kernel<<<500, 256, 0, stream>>>(cxp, cyp, czp, qkvb, out_w, out_b, out);
}

// Round 7
// 127.317 us; speedup vs baseline: 1.0831x; 1.0831x over previous
//
#include <hip/hip_runtime.h>
#include <math.h>

#define N_NODES 2000
#define E_DIM   128
#define QKV_W   384
#define LDA     36   // A-tile leading dim pad

// ---------------------------------------------------------------------------
// Kernel 1: fused prep + qkv. (unchanged — not the bottleneck)
// ---------------------------------------------------------------------------
__global__ __launch_bounds__(256) void prep_qkv_kernel(
    const float* __restrict__ x, const float* __restrict__ coords9,
    const float* __restrict__ ps, const float* __restrict__ pe_w,
    const float* __restrict__ pe_b, const float* __restrict__ pe_g,
    const float* __restrict__ pe_bt, const float* __restrict__ in_w,
    const float* __restrict__ in_b,
    float* __restrict__ cx_, float* __restrict__ cy_, float* __restrict__ cz_,
    float* __restrict__ qkv)
{
    __shared__ __align__(16) float As[E_DIM * LDA]; // As[c][r]
    int tid = threadIdx.x;
    int rt = blockIdx.x / 3, ct = blockIdx.x % 3;
    int rbase = rt * 32, cbase = ct * 128;
    int g = tid >> 5, lane = tid & 31;

    #pragma unroll
    for (int rr = 0; rr < 4; ++rr) {
        int rl = rr * 8 + g;
        int row = rbase + rl;
        bool vr = (row < N_NODES);
        float cx = 0.f, cy = 0.f, cz = 0.f;
        if (vr) {
            const float* c9 = coords9 + row * 9;
            cx = (c9[0] + c9[3] + c9[6]) * (1.0f / 3.0f);
            cy = (c9[1] + c9[4] + c9[7]) * (1.0f / 3.0f);
            cz = (c9[2] + c9[5] + c9[8]) * (1.0f / 3.0f);
        }
        if (ct == 0 && vr && lane == 0) { cx_[row] = cx; cy_[row] = cy; cz_[row] = cz; }

        #pragma unroll
        for (int k = 0; k < 3; ++k) {
            int c = lane + 32 * k;
            float v = vr ? (x[row * E_DIM + c] + ps[c]) : 0.f;
            As[c * LDA + rl] = v;
        }

        int j = lane;
        float h = cx * pe_w[j] + cy * pe_w[32 + j] + cz * pe_w[64 + j] + pe_b[j];
        float ge = 0.5f * h * (1.0f + erff(h * 0.7071067811865476f)); // exact GELU
        float s = ge;
        #pragma unroll
        for (int m = 16; m >= 1; m >>= 1) s += __shfl_xor(s, m);
        float mu = s * (1.0f / 32.0f);
        float d = ge - mu;
        float v2 = d * d;
        #pragma unroll
        for (int m = 16; m >= 1; m >>= 1) v2 += __shfl_xor(v2, m);
        float var = v2 * (1.0f / 32.0f);
        float y = d * (1.0f / sqrtf(var + 1e-5f)) * pe_g[j] + pe_bt[j];
        As[(96 + j) * LDA + rl] = vr ? y : 0.f;
    }
    __syncthreads();

    int cg = tid & 31, rg = tid >> 5;
    int c0 = cbase + cg * 4, r0 = rg * 4;
    float acc[4][4];
    #pragma unroll
    for (int i = 0; i < 4; ++i)
        #pragma unroll
        for (int jj = 0; jj < 4; ++jj) acc[i][jj] = 0.f;

    for (int k0 = 0; k0 < 128; k0 += 4) {
        float4 a0 = *(const float4*)&As[(k0 + 0) * LDA + r0];
        float4 a1 = *(const float4*)&As[(k0 + 1) * LDA + r0];
        float4 a2 = *(const float4*)&As[(k0 + 2) * LDA + r0];
        float4 a3 = *(const float4*)&As[(k0 + 3) * LDA + r0];
        #pragma unroll
        for (int ci = 0; ci < 4; ++ci) {
            float4 b = *(const float4*)&in_w[(c0 + ci) * E_DIM + k0];
            acc[0][ci] += a0.x * b.x + a1.x * b.y + a2.x * b.z + a3.x * b.w;
            acc[1][ci] += a0.y * b.x + a1.y * b.y + a2.y * b.z + a3.y * b.w;
            acc[2][ci] += a0.z * b.x + a1.z * b.y + a2.z * b.z + a3.z * b.w;
            acc[3][ci] += a0.w * b.x + a1.w * b.y + a2.w * b.z + a3.w * b.w;
        }
    }

    #pragma unroll
    for (int ri = 0; ri < 4; ++ri) {
        int row = rbase + r0 + ri;
        if (row < N_NODES) {
            float4 o4;
            o4.x = acc[ri][0] + in_b[c0 + 0];
            o4.y = acc[ri][1] + in_b[c0 + 1];
            o4.z = acc[ri][2] + in_b[c0 + 2];
            o4.w = acc[ri][3] + in_b[c0 + 3];
            *(float4*)&qkv[row * QKV_W + c0] = o4;
        }
    }
}

// ---------------------------------------------------------------------------
// Kernel 2 (R7): block-per-row (2000 blocks = 8000 waves, R5 parallelism)
// with WAVE-LOCAL selection (R6 mechanism) and only 4 block barriers.
// Each wave exactly selects top-32 of its own ~500-node subset (wave-private
// LDS, wave-synchronous); 4x32 candidates merged exactly by (key,idx) rank
// over 128 — the global top-32 is contained in the union. Tie-break and
// softmax semantics identical to the verified R2-R6 kernels.
// ---------------------------------------------------------------------------
__device__ __forceinline__ float sanitize(float v)
{
    v = (v == v) ? v : 0.f;
    return fminf(fmaxf(v, -1e4f), 1e4f);
}

__global__ __launch_bounds__(256) void attn_proj_kernel(
    const float* __restrict__ cx_, const float* __restrict__ cy_,
    const float* __restrict__ cz_, const float* __restrict__ qkv,
    const float* __restrict__ out_w, const float* __restrict__ out_b,
    float* __restrict__ out)
{
    __shared__ __align__(16) unsigned int hist[4][256]; // per-wave
    __shared__ int eqIdx[4][128];
    __shared__ unsigned int eqKey[4][128];
    __shared__ int cnt[4][2];                  // [0]=sel, [1]=eq (per wave)
    __shared__ unsigned int candKey[128];      // 4 waves x 32 candidates
    __shared__ int candIdx[128];
    __shared__ int topk[32];
    __shared__ __align__(16) float qs[128];
    __shared__ float pr[256];
    __shared__ __align__(16) float os[128];

    int tid = threadIdx.x;
    int row = blockIdx.x;
    int lane = tid & 63, w = tid >> 6;

    float cix = cx_[row], ciy = cy_[row], ciz = cz_[row];

    // ---- wave-local subset: j = 64w + lane + 256*it, it in [0,8)
    // (waves 0-2: 512 nodes, wave 3: 464 — all >= 32)
    unsigned int kb[8];
    bool valid[8];
    float lmin = __int_as_float(0x7f800000);
    float lmax = __int_as_float(0xff800000);
    {
        #pragma clang fp contract(off)  // match reference bit pattern exactly
        #pragma unroll
        for (int it = 0; it < 8; ++it) {
            int j = 64 * w + lane + 256 * it;
            valid[it] = (j < N_NODES);
            float key = __int_as_float(0x7f800000);
            if (valid[it]) {
                float dx = cix - cx_[j];
                float dy = ciy - cy_[j];
                float dz = ciz - cz_[j];
                float a = dx * dx;
                float b2 = dy * dy;
                float c = dz * dz;
                float d2 = ((a + b2) + c) + 1e-20f;
                key = sqrtf(d2);
                lmin = fminf(lmin, key);
                lmax = fmaxf(lmax, key);
            }
            kb[it] = __float_as_uint(key);
        }
    }
    // wave min/max of this wave's keys
    #pragma unroll
    for (int m = 32; m >= 1; m >>= 1) {
        lmin = fminf(lmin, __shfl_xor(lmin, m));
        lmax = fmaxf(lmax, __shfl_xor(lmax, m));
    }
    float lo = lmin;
    float scale = 255.0f / fmaxf(lmax - lmin, 1e-30f);

    // ---- wave-private linear-value histogram (wave-synchronous)
    *(uint4*)&hist[w][4 * lane] = make_uint4(0u, 0u, 0u, 0u);
    if (lane == 0) { cnt[w][0] = 0; cnt[w][1] = 0; }
    __builtin_amdgcn_wave_barrier();
    int bins[8];
    #pragma unroll
    for (int it = 0; it < 8; ++it) {
        int bin = 255;
        if (valid[it]) {
            float key = __uint_as_float(kb[it]);
            bin = (int)((key - lo) * scale);
            bin = min(max(bin, 0), 255);
            atomicAdd(&hist[w][bin], 1u);
        }
        bins[it] = bin;
    }
    __builtin_amdgcn_wave_barrier();

    // ---- in-wave prefix scan of 256 bins (4/lane); boundary bin of wave
    uint4 h4 = *(const uint4*)&hist[w][4 * lane];
    int s0 = (int)h4.x;
    int s1 = s0 + (int)h4.y;
    int s2 = s1 + (int)h4.z;
    int tot = s2 + (int)h4.w;
    int incl = tot;
    #pragma unroll
    for (int dd = 1; dd < 64; dd <<= 1) {
        int u = __shfl_up(incl, dd);
        if (lane >= dd) incl += u;
    }
    int excl = incl - tot;
    int c0 = excl + s0, c1 = excl + s1, c2 = excl + s2, c3 = excl + tot;
    int cand = 256, candN = 0;
    if (excl < 32 && c0 >= 32)    { cand = 4 * lane;     candN = excl; }
    else if (c0 < 32 && c1 >= 32) { cand = 4 * lane + 1; candN = c0; }
    else if (c1 < 32 && c2 >= 32) { cand = 4 * lane + 2; candN = c1; }
    else if (c2 < 32 && c3 >= 32) { cand = 4 * lane + 3; candN = c2; }
    int candV = (cand << 8) | candN;
    #pragma unroll
    for (int m = 32; m >= 1; m >>= 1) candV = min(candV, __shfl_xor(candV, m));
    int b = candV >> 8;
    int req = 32 - (candV & 255);

    // ---- wave collect into its 32-candidate slab
    #pragma unroll
    for (int it = 0; it < 8; ++it) {
        if (valid[it]) {
            int bin = bins[it];
            int j = 64 * w + lane + 256 * it;
            if (bin < b) {
                int p = atomicAdd(&cnt[w][0], 1);
                candIdx[w * 32 + p] = j;
                candKey[w * 32 + p] = kb[it];
            } else if (bin == b) {
                int e = atomicAdd(&cnt[w][1], 1);
                if (e < 128) { eqIdx[w][e] = j; eqKey[w][e] = kb[it]; }
            }
        }
    }
    __builtin_amdgcn_wave_barrier();

    // ---- wave boundary-bin resolution: exact rank on (uint32 key, index)
    int eq = min(cnt[w][1], 128);
    for (int e = lane; e < eq; e += 64) {
        int myIdx = eqIdx[w][e];
        unsigned int myKey = eqKey[w][e];
        int rank = 0;
        for (int u = 0; u < eq; ++u) {
            unsigned int ku = eqKey[w][u];
            rank += (ku < myKey || (ku == myKey && eqIdx[w][u] < myIdx)) ? 1 : 0;
        }
        if (rank < req) {
            int p = atomicAdd(&cnt[w][0], 1);
            candIdx[w * 32 + p] = myIdx;
            candKey[w * 32 + p] = myKey;
        }
    }
    __syncthreads();   // barrier 1: all 128 candidates visible

    // ---- exact merge: rank each of 128 candidates over all 128 by (key,idx);
    // ranks are a permutation -> thread with rank<32 writes topk[rank].
    // threads 128-255 stage q concurrently.
    if (tid < 128) {
        unsigned int myKey = candKey[tid];
        int myIdx = candIdx[tid];
        int rank = 0;
        #pragma unroll 4
        for (int u = 0; u < 128; ++u) {
            unsigned int ku = candKey[u];
            rank += (ku < myKey || (ku == myKey && candIdx[u] < myIdx)) ? 1 : 0;
        }
        if (rank < 32) topk[rank] = myIdx;
    } else {
        qs[tid - 128] = qkv[row * QKV_W + (tid - 128)];
    }
    __syncthreads();   // barrier 2: topk + qs ready

    // ---- scores + softmax: thread = (head hh, slot j)
    {
        int hh = tid >> 5, j = tid & 31;
        int jj = topk[j];
        const float4* kp = (const float4*)&qkv[jj * QKV_W + 128 + hh * 16];
        const float4* qp = (const float4*)&qs[hh * 16];
        float s = 0.f;
        #pragma unroll
        for (int i = 0; i < 4; ++i) {
            float4 kv = kp[i], qv = qp[i];
            s += qv.x * kv.x + qv.y * kv.y + qv.z * kv.z + qv.w * kv.w;
        }
        s *= 0.25f;                            // 1/sqrt(16)
        float m = s;
        #pragma unroll
        for (int msk = 16; msk >= 1; msk >>= 1) m = fmaxf(m, __shfl_xor(m, msk));
        float pe = expf(s - m);
        float su = pe;
        #pragma unroll
        for (int msk = 16; msk >= 1; msk >>= 1) su += __shfl_xor(su, msk);
        pr[tid] = pe / su;
    }
    __syncthreads();   // barrier 3: pr ready

    // ---- o = probs @ v (128 threads, single chain)
    if (tid < 128) {
        int hh = tid >> 4;
        float acc = 0.f;
        #pragma unroll
        for (int j = 0; j < 32; ++j) {
            int jj = topk[j];
            acc += pr[hh * 32 + j] * qkv[jj * QKV_W + 256 + tid];
        }
        os[tid] = acc;
    }
    __syncthreads();   // barrier 4: os ready

    // ---- fused out-projection + sanitize (128 threads)
    if (tid < 128) {
        const float* wr = out_w + tid * E_DIM;
        float a = 0.f;
        #pragma unroll
        for (int e = 0; e < 128; e += 4) {
            float4 w4 = *(const float4*)&wr[e];
            float4 o4 = *(const float4*)&os[e];
            a += o4.x * w4.x + o4.y * w4.y + o4.z * w4.z + o4.w * w4.w;
        }
        out[row * E_DIM + tid] = sanitize(a + out_b[tid]);
    }
}

// ---------------------------------------------------------------------------
extern "C" void kernel_launch(void* const* d_in, const int* in_sizes, int n_in,
                              void* d_out, int out_size, void* d_ws, size_t ws_size,
                              hipStream_t stream)
{
    const float* x      = (const float*)d_in[0];
    const float* coords = (const float*)d_in[1];
    const float* ps     = (const float*)d_in[2];
    const float* pe_w   = (const float*)d_in[3];
    const float* pe_b   = (const float*)d_in[4];
    const float* pe_g   = (const float*)d_in[5];
    const float* pe_bt  = (const float*)d_in[6];
    const float* in_w   = (const float*)d_in[7];
    const float* in_b   = (const float*)d_in[8];
    const float* out_w  = (const float*)d_in[9];
    const float* out_b  = (const float*)d_in[10];
    float* out = (float*)d_out;

    float* ws  = (float*)d_ws;
    float* cxp = ws;            // 2048
    float* cyp = ws + 2048;     // 2048
    float* czp = ws + 4096;     // 2048
    float* qkvb = ws + 6144;    // 2000*384

    prep_qkv_kernel<<<189, 256, 0, stream>>>(x, coords, ps, pe_w, pe_b, pe_g, pe_bt,
                                             in_w, in_b, cxp, cyp, czp, qkvb);
    attn_proj_kernel<<<2000, 256, 0, stream>>>(cxp, cyp, czp, qkvb, out_w, out_b, out);
}

// Round 8
// 123.565 us; speedup vs baseline: 1.1160x; 1.0304x over previous
//
#include <hip/hip_runtime.h>
#include <math.h>

#define N_NODES 2000
#define E_DIM   128
#define QKV_W   384
#define LDA     36   // A-tile leading dim pad

// ---------------------------------------------------------------------------
// Kernel 1: fused prep + qkv. (unchanged — not the bottleneck)
// ---------------------------------------------------------------------------
__global__ __launch_bounds__(256) void prep_qkv_kernel(
    const float* __restrict__ x, const float* __restrict__ coords9,
    const float* __restrict__ ps, const float* __restrict__ pe_w,
    const float* __restrict__ pe_b, const float* __restrict__ pe_g,
    const float* __restrict__ pe_bt, const float* __restrict__ in_w,
    const float* __restrict__ in_b,
    float* __restrict__ cx_, float* __restrict__ cy_, float* __restrict__ cz_,
    float* __restrict__ qkv)
{
    __shared__ __align__(16) float As[E_DIM * LDA]; // As[c][r]
    int tid = threadIdx.x;
    int rt = blockIdx.x / 3, ct = blockIdx.x % 3;
    int rbase = rt * 32, cbase = ct * 128;
    int g = tid >> 5, lane = tid & 31;

    #pragma unroll
    for (int rr = 0; rr < 4; ++rr) {
        int rl = rr * 8 + g;
        int row = rbase + rl;
        bool vr = (row < N_NODES);
        float cx = 0.f, cy = 0.f, cz = 0.f;
        if (vr) {
            const float* c9 = coords9 + row * 9;
            cx = (c9[0] + c9[3] + c9[6]) * (1.0f / 3.0f);
            cy = (c9[1] + c9[4] + c9[7]) * (1.0f / 3.0f);
            cz = (c9[2] + c9[5] + c9[8]) * (1.0f / 3.0f);
        }
        if (ct == 0 && vr && lane == 0) { cx_[row] = cx; cy_[row] = cy; cz_[row] = cz; }

        #pragma unroll
        for (int k = 0; k < 3; ++k) {
            int c = lane + 32 * k;
            float v = vr ? (x[row * E_DIM + c] + ps[c]) : 0.f;
            As[c * LDA + rl] = v;
        }

        int j = lane;
        float h = cx * pe_w[j] + cy * pe_w[32 + j] + cz * pe_w[64 + j] + pe_b[j];
        float ge = 0.5f * h * (1.0f + erff(h * 0.7071067811865476f)); // exact GELU
        float s = ge;
        #pragma unroll
        for (int m = 16; m >= 1; m >>= 1) s += __shfl_xor(s, m);
        float mu = s * (1.0f / 32.0f);
        float d = ge - mu;
        float v2 = d * d;
        #pragma unroll
        for (int m = 16; m >= 1; m >>= 1) v2 += __shfl_xor(v2, m);
        float var = v2 * (1.0f / 32.0f);
        float y = d * (1.0f / sqrtf(var + 1e-5f)) * pe_g[j] + pe_bt[j];
        As[(96 + j) * LDA + rl] = vr ? y : 0.f;
    }
    __syncthreads();

    int cg = tid & 31, rg = tid >> 5;
    int c0 = cbase + cg * 4, r0 = rg * 4;
    float acc[4][4];
    #pragma unroll
    for (int i = 0; i < 4; ++i)
        #pragma unroll
        for (int jj = 0; jj < 4; ++jj) acc[i][jj] = 0.f;

    for (int k0 = 0; k0 < 128; k0 += 4) {
        float4 a0 = *(const float4*)&As[(k0 + 0) * LDA + r0];
        float4 a1 = *(const float4*)&As[(k0 + 1) * LDA + r0];
        float4 a2 = *(const float4*)&As[(k0 + 2) * LDA + r0];
        float4 a3 = *(const float4*)&As[(k0 + 3) * LDA + r0];
        #pragma unroll
        for (int ci = 0; ci < 4; ++ci) {
            float4 b = *(const float4*)&in_w[(c0 + ci) * E_DIM + k0];
            acc[0][ci] += a0.x * b.x + a1.x * b.y + a2.x * b.z + a3.x * b.w;
            acc[1][ci] += a0.y * b.x + a1.y * b.y + a2.y * b.z + a3.y * b.w;
            acc[2][ci] += a0.z * b.x + a1.z * b.y + a2.z * b.z + a3.z * b.w;
            acc[3][ci] += a0.w * b.x + a1.w * b.y + a2.w * b.z + a3.w * b.w;
        }
    }

    #pragma unroll
    for (int ri = 0; ri < 4; ++ri) {
        int row = rbase + r0 + ri;
        if (row < N_NODES) {
            float4 o4;
            o4.x = acc[ri][0] + in_b[c0 + 0];
            o4.y = acc[ri][1] + in_b[c0 + 1];
            o4.z = acc[ri][2] + in_b[c0 + 2];
            o4.w = acc[ri][3] + in_b[c0 + 3];
            *(float4*)&qkv[row * QKV_W + c0] = o4;
        }
    }
}

// ---------------------------------------------------------------------------
// Kernel 2 (R8): R5 structure (block-wide selection, 2000 blocks) with 6
// block barriers instead of 8: (a) 256-bin scan done by wave 0 alone
// (in-wave, R6-validated) while threads 64-191 stage q; (b) softmax+PV fused
// wave-privately — wave w owns heads 2w,2w+1 end-to-end, pr never crosses
// waves. Selection semantics and math identical to verified R2-R7 kernels.
// ---------------------------------------------------------------------------
__device__ __forceinline__ float sanitize(float v)
{
    v = (v == v) ? v : 0.f;
    return fminf(fmaxf(v, -1e4f), 1e4f);
}

__global__ __launch_bounds__(256) void attn_proj_kernel(
    const float* __restrict__ cx_, const float* __restrict__ cy_,
    const float* __restrict__ cz_, const float* __restrict__ qkv,
    const float* __restrict__ out_w, const float* __restrict__ out_b,
    float* __restrict__ out)
{
    __shared__ unsigned int hist[256];
    __shared__ float wMin[4], wMax[4];
    __shared__ int sh_b, sh_req, sh_sel, sh_eq;
    __shared__ int topk[32];
    __shared__ int eqIdx[256];
    __shared__ unsigned int eqKey[256];
    __shared__ __align__(16) float qs[128];
    __shared__ float prW[256];          // wave-private slabs: prW[w*64 + lane]
    __shared__ __align__(16) float os[128];

    int tid = threadIdx.x;
    int row = blockIdx.x;
    int lane = tid & 63, w = tid >> 6;

    float cix = cx_[row], ciy = cy_[row], ciz = cz_[row];
    unsigned int kbits[8];
    int bins[8];
    bool valid[8];
    float lmin = __int_as_float(0x7f800000);
    float lmax = __int_as_float(0xff800000);
    {
        #pragma clang fp contract(off)  // match reference bit pattern exactly
        #pragma unroll
        for (int l = 0; l < 8; ++l) {
            int j = tid + 256 * l;
            valid[l] = (j < N_NODES);
            float key = __int_as_float(0x7f800000);
            if (valid[l]) {
                float dx = cix - cx_[j];
                float dy = ciy - cy_[j];
                float dz = ciz - cz_[j];
                float a = dx * dx;
                float b2 = dy * dy;
                float c = dz * dz;
                float d2 = ((a + b2) + c) + 1e-20f;
                key = sqrtf(d2);
                lmin = fminf(lmin, key);
                lmax = fmaxf(lmax, key);
            }
            kbits[l] = __float_as_uint(key);
        }
    }

    // ---- block min/max (wave reduce -> LDS); zero hist; init counters
    #pragma unroll
    for (int m = 32; m >= 1; m >>= 1) {
        lmin = fminf(lmin, __shfl_xor(lmin, m));
        lmax = fmaxf(lmax, __shfl_xor(lmax, m));
    }
    if (lane == 0) { wMin[w] = lmin; wMax[w] = lmax; }
    hist[tid] = 0u;
    if (tid == 0) { sh_sel = 0; sh_eq = 0; }
    __syncthreads();                                       // barrier 1

    // all threads compute lo/scale redundantly
    float lo = fminf(fminf(wMin[0], wMin[1]), fminf(wMin[2], wMin[3]));
    float hi = fmaxf(fmaxf(wMax[0], wMax[1]), fmaxf(wMax[2], wMax[3]));
    float scale = 255.0f / fmaxf(hi - lo, 1e-30f);

    // ---- linear-value histogram; cache bins in registers
    #pragma unroll
    for (int l = 0; l < 8; ++l) {
        int bin = 255;
        if (valid[l]) {
            float key = __uint_as_float(kbits[l]);
            bin = (int)((key - lo) * scale);
            bin = min(max(bin, 0), 255);
            atomicAdd(&hist[bin], 1u);
        }
        bins[l] = bin;
    }
    __syncthreads();                                       // barrier 2

    // ---- wave 0: in-wave 256-bin scan (4 bins/lane) -> boundary bin;
    //      threads 64-191: stage q concurrently
    if (w == 0) {
        uint4 h4 = *(const uint4*)&hist[4 * lane];
        int s0 = (int)h4.x;
        int s1 = s0 + (int)h4.y;
        int s2 = s1 + (int)h4.z;
        int tot = s2 + (int)h4.w;
        int incl = tot;
        #pragma unroll
        for (int dd = 1; dd < 64; dd <<= 1) {
            int u = __shfl_up(incl, dd);
            if (lane >= dd) incl += u;
        }
        int excl = incl - tot;
        int c0 = excl + s0, c1 = excl + s1, c2 = excl + s2, c3 = excl + tot;
        int cand = 256, candN = 0;
        if (excl < 32 && c0 >= 32)    { cand = 4 * lane;     candN = excl; }
        else if (c0 < 32 && c1 >= 32) { cand = 4 * lane + 1; candN = c0; }
        else if (c1 < 32 && c2 >= 32) { cand = 4 * lane + 2; candN = c1; }
        else if (c2 < 32 && c3 >= 32) { cand = 4 * lane + 3; candN = c2; }
        int candV = (cand << 8) | candN;
        #pragma unroll
        for (int m = 32; m >= 1; m >>= 1) candV = min(candV, __shfl_xor(candV, m));
        if (lane == 0) { sh_b = candV >> 8; sh_req = 32 - (candV & 255); }
    } else if (tid < 192) {
        qs[tid - 64] = qkv[row * QKV_W + (tid - 64)];
    }
    __syncthreads();                                       // barrier 3

    int b = sh_b;
    int req = sh_req;

    // ---- collect (bins from registers)
    #pragma unroll
    for (int l = 0; l < 8; ++l) {
        if (valid[l]) {
            int bin = bins[l];
            int j = tid + 256 * l;
            if (bin < b) {
                int p = atomicAdd(&sh_sel, 1);
                topk[p] = j;
            } else if (bin == b) {
                int e = atomicAdd(&sh_eq, 1);
                if (e < 256) { eqIdx[e] = j; eqKey[e] = kbits[l]; }
            }
        }
    }
    __syncthreads();                                       // barrier 4

    // ---- boundary bin: exact rank on (uint32 key, index), lower index wins
    int eq = min(sh_eq, 256);
    if (tid < eq) {
        int myIdx = eqIdx[tid];
        unsigned int myKey = eqKey[tid];
        int rank = 0;
        for (int u = 0; u < eq; ++u) {
            unsigned int ku = eqKey[u];
            rank += (ku < myKey || (ku == myKey && eqIdx[u] < myIdx)) ? 1 : 0;
        }
        if (rank < req) {
            int p = atomicAdd(&sh_sel, 1);
            topk[p] = myIdx;
        }
    }
    __syncthreads();                                       // barrier 5

    // ---- scores + softmax + PV, wave-private: wave w owns heads 2w, 2w+1
    {
        int hh = 2 * w + (lane >> 5);          // this lane's head
        int j = lane & 31;                     // this lane's slot
        int jj = topk[j];
        const float4* kp = (const float4*)&qkv[jj * QKV_W + 128 + hh * 16];
        const float4* qp = (const float4*)&qs[hh * 16];
        float s = 0.f;
        #pragma unroll
        for (int i = 0; i < 4; ++i) {
            float4 kv = kp[i], qv = qp[i];
            s += qv.x * kv.x + qv.y * kv.y + qv.z * kv.z + qv.w * kv.w;
        }
        s *= 0.25f;                            // 1/sqrt(16)
        float m = s;
        #pragma unroll
        for (int msk = 16; msk >= 1; msk >>= 1) m = fmaxf(m, __shfl_xor(m, msk));
        float pe = expf(s - m);
        float su = pe;
        #pragma unroll
        for (int msk = 16; msk >= 1; msk >>= 1) su += __shfl_xor(su, msk);
        prW[tid] = pe / su;                    // slab: prW[w*64 + (hl*32 + j)]
    }
    __builtin_amdgcn_wave_barrier();           // wave-order LDS coherence

    // PV: lane -> dim c = 32w + (lane&31); j-half jh = lane>>5 (16 slots);
    // combine halves via shfl_xor(32). pr stays wave-private.
    {
        int cl = lane & 31;
        int c = 32 * w + cl;                   // global output dim (head c>>4)
        int hl = cl >> 4;                      // head-local index in wave slab
        int jh = lane >> 5;                    // which half of the 32 slots
        float acc = 0.f;
        #pragma unroll
        for (int t = 0; t < 16; ++t) {
            int sl = jh * 16 + t;
            int jx = topk[sl];
            acc += prW[w * 64 + hl * 32 + sl] * qkv[jx * QKV_W + 256 + c];
        }
        acc += __shfl_xor(acc, 32);            // both halves now hold full sum
        if (lane < 32) os[c] = acc;
    }
    __syncthreads();                                       // barrier 6

    // ---- fused out-projection + sanitize (128 threads)
    if (tid < 128) {
        const float* wr = out_w + tid * E_DIM;
        float a = 0.f;
        #pragma unroll
        for (int e = 0; e < 128; e += 4) {
            float4 w4 = *(const float4*)&wr[e];
            float4 o4 = *(const float4*)&os[e];
            a += o4.x * w4.x + o4.y * w4.y + o4.z * w4.z + o4.w * w4.w;
        }
        out[row * E_DIM + tid] = sanitize(a + out_b[tid]);
    }
}

// ---------------------------------------------------------------------------
extern "C" void kernel_launch(void* const* d_in, const int* in_sizes, int n_in,
                              void* d_out, int out_size, void* d_ws, size_t ws_size,
                              hipStream_t stream)
{
    const float* x      = (const float*)d_in[0];
    const float* coords = (const float*)d_in[1];
    const float* ps     = (const float*)d_in[2];
    const float* pe_w   = (const float*)d_in[3];
    const float* pe_b   = (const float*)d_in[4];
    const float* pe_g   = (const float*)d_in[5];
    const float* pe_bt  = (const float*)d_in[6];
    const float* in_w   = (const float*)d_in[7];
    const float* in_b   = (const float*)d_in[8];
    const float* out_w  = (const float*)d_in[9];
    const float* out_b  = (const float*)d_in[10];
    float* out = (float*)d_out;

    float* ws  = (float*)d_ws;
    float* cxp = ws;            // 2048
    float* cyp = ws + 2048;     // 2048
    float* czp = ws + 4096;     // 2048
    float* qkvb = ws + 6144;    // 2000*384

    prep_qkv_kernel<<<189, 256, 0, stream>>>(x, coords, ps, pe_w, pe_b, pe_g, pe_bt,
                                             in_w, in_b, cxp, cyp, czp, qkvb);
    attn_proj_kernel<<<2000, 256, 0, stream>>>(cxp, cyp, czp, qkvb, out_w, out_b, out);
}